// Round 6
// baseline (392.213 us; speedup 1.0000x reference)
//
#include <hip/hip_runtime.h>

typedef __bf16 bf16;
typedef __bf16 bf16x8 __attribute__((ext_vector_type(8)));
typedef __bf16 bf16x4 __attribute__((ext_vector_type(4)));
typedef _Float16 f16;
typedef _Float16 f16x2 __attribute__((ext_vector_type(2)));
typedef _Float16 f16x4 __attribute__((ext_vector_type(4)));
typedef _Float16 f16x8 __attribute__((ext_vector_type(8)));
typedef float f32x4 __attribute__((ext_vector_type(4)));

__device__ __forceinline__ f32x4 mfma_qk(bf16x8 a, bf16x8 b, f32x4 c) {
    return __builtin_amdgcn_mfma_f32_16x16x32_bf16(a, b, c, 0, 0, 0);
}
__device__ __forceinline__ f32x4 mfma_pv(f16x4 a, f16x4 b, f32x4 c) {
    return __builtin_amdgcn_mfma_f32_16x16x16f16(a, b, c, 0, 0, 0);
}

// async global -> LDS, 16 bytes per lane (dest = wave-uniform base + lane*16)
#define GLOAD_LDS16(gp, lp)                                                    \
    __builtin_amdgcn_global_load_lds(                                          \
        (const __attribute__((address_space(1))) unsigned int*)(gp),           \
        (__attribute__((address_space(3))) unsigned int*)(lp), 16, 0, 0)

// ---------------------------------------------------------------------------
// Cast the four 1024x1024 fp32 weights + key_value (8M floats) to bf16.
// ---------------------------------------------------------------------------
__global__ __launch_bounds__(256) void cast_inputs(
    const float* __restrict__ w0, const float* __restrict__ w1,
    const float* __restrict__ w2, const float* __restrict__ w3,
    const float* __restrict__ kv, bf16* __restrict__ Wb,
    bf16* __restrict__ KVa) {
    long i4 = (long)blockIdx.x * 256 + threadIdx.x;  // float4 index
    const float* src;
    bf16* dst;
    long loc;
    if (i4 < 1048576) {  // 4 weights x 262144 float4
        int which = (int)(i4 >> 18);
        loc = (i4 & 262143) << 2;
        src = which == 0 ? w0 : which == 1 ? w1 : which == 2 ? w2 : w3;
        dst = Wb + ((long)which << 20);
    } else {             // key_value: 2097152 float4
        loc = (i4 - 1048576) << 2;
        src = kv;
        dst = KVa;
    }
    float4 f = *(const float4*)(src + loc);
    bf16x4 o;
    o[0] = (bf16)f.x; o[1] = (bf16)f.y; o[2] = (bf16)f.z; o[3] = (bf16)f.w;
    *(bf16x4*)(dst + loc) = o;
}

// ---------------------------------------------------------------------------
// C[M,N] = A[M,K] @ W[N,K]^T + bias. M=8192, N=K=1024.
// 128x128 tile, BK=32, 4 waves each 64x64 (m97 pattern).
// AT: float (convert during staging) or bf16 (global_load_lds).
// OM: 0 = bf16 row-major, 1 = f32 row-major, 2 = fp16 V^T [b,h,d,skv] via
//     LDS transpose epilogue (coalesced 256B stores).
// ---------------------------------------------------------------------------
template <typename AT, int OM>
__global__ __launch_bounds__(256) void gemm_bt(
    const AT* __restrict__ A, const bf16* __restrict__ Wt,
    const float* __restrict__ bias, void* __restrict__ Yv) {
    constexpr int Kd = 1024, Nd = 1024;
    constexpr int TP = 132;  // transpose-epilogue row stride (pad 4)
    __shared__ __align__(16) bf16 smem[OM == 2 ? 128 * TP : 8192];
    bf16* As = smem;
    bf16* Bs = smem + 4096;
    const int tid = threadIdx.x;
    const int wid = tid >> 6, lane = tid & 63;
    const int l16 = lane & 15, quad = lane >> 4;
    const int n0 = blockIdx.x * 128, m0 = blockIdx.y * 128;
    const int mh = (wid >> 1) * 64, nh = (wid & 1) * 64;

    f32x4 acc[4][4];
#pragma unroll
    for (int i = 0; i < 4; ++i)
#pragma unroll
        for (int j = 0; j < 4; ++j) acc[i][j] = (f32x4){0.f, 0.f, 0.f, 0.f};

    const int c0 = tid, c1 = tid + 256;       // 16B chunk ids for async staging
    const int sr = tid >> 1, sc = (tid & 1) * 16;  // fp32-A staging coords

    for (int k0 = 0; k0 < Kd; k0 += 32) {
        GLOAD_LDS16(Wt + (long)(n0 + (c0 >> 2)) * Kd + k0 + (c0 & 3) * 8, &Bs[c0 * 8]);
        GLOAD_LDS16(Wt + (long)(n0 + (c1 >> 2)) * Kd + k0 + (c1 & 3) * 8, &Bs[(long)c1 * 8]);
        if constexpr (sizeof(AT) == 4) {
            const float* ap = (const float*)A + (long)(m0 + sr) * Kd + k0 + sc;
            float4 f0 = *(const float4*)(ap + 0);
            float4 f1 = *(const float4*)(ap + 4);
            float4 f2 = *(const float4*)(ap + 8);
            float4 f3 = *(const float4*)(ap + 12);
            bf16x8 p0, p1;
            p0[0] = (bf16)f0.x; p0[1] = (bf16)f0.y; p0[2] = (bf16)f0.z; p0[3] = (bf16)f0.w;
            p0[4] = (bf16)f1.x; p0[5] = (bf16)f1.y; p0[6] = (bf16)f1.z; p0[7] = (bf16)f1.w;
            p1[0] = (bf16)f2.x; p1[1] = (bf16)f2.y; p1[2] = (bf16)f2.z; p1[3] = (bf16)f2.w;
            p1[4] = (bf16)f3.x; p1[5] = (bf16)f3.y; p1[6] = (bf16)f3.z; p1[7] = (bf16)f3.w;
            *(bf16x8*)&As[sr * 32 + sc] = p0;
            *(bf16x8*)&As[sr * 32 + sc + 8] = p1;
        } else {
            GLOAD_LDS16((const bf16*)A + (long)(m0 + (c0 >> 2)) * Kd + k0 + (c0 & 3) * 8, &As[c0 * 8]);
            GLOAD_LDS16((const bf16*)A + (long)(m0 + (c1 >> 2)) * Kd + k0 + (c1 & 3) * 8, &As[(long)c1 * 8]);
        }
        __syncthreads();
        bf16x8 af[4], bq[4];
#pragma unroll
        for (int i = 0; i < 4; ++i)
            af[i] = *(const bf16x8*)&As[(mh + i * 16 + l16) * 32 + quad * 8];
#pragma unroll
        for (int i = 0; i < 4; ++i)
            bq[i] = *(const bf16x8*)&Bs[(nh + i * 16 + l16) * 32 + quad * 8];
#pragma unroll
        for (int i = 0; i < 4; ++i)
#pragma unroll
            for (int j = 0; j < 4; ++j)
                acc[i][j] = mfma_qk(af[i], bq[j], acc[i][j]);
        __syncthreads();
    }

    if constexpr (OM == 2) {
        // stage transposed tile Ts[col][row] as fp16 pairs
#pragma unroll
        for (int j = 0; j < 4; ++j) {
            const int col = nh + j * 16 + l16;
            const float bv = bias[n0 + col];
#pragma unroll
            for (int i = 0; i < 4; ++i)
#pragma unroll
                for (int p = 0; p < 2; ++p) {
                    f16x2 pk2;
                    pk2[0] = (f16)(acc[i][j][p * 2 + 0] + bv);
                    pk2[1] = (f16)(acc[i][j][p * 2 + 1] + bv);
                    *(f16x2*)&smem[col * TP + mh + i * 16 + quad * 4 + p * 2] = pk2;
                }
        }
        __syncthreads();
        // coalesced stores: Vt[((b*16+h)*64+d)*2048 + skv]  (raw 16B copies)
        const int b_ = m0 >> 11, skv0 = m0 & 2047;
        const int rowc = tid & 15;
#pragma unroll
        for (int c = 0; c < 8; ++c) {
            const int col = (tid >> 4) + c * 16;
            const int colg = n0 + col;
            bf16x8 v = *(const bf16x8*)&smem[col * TP + rowc * 8];
            const long base = ((long)((b_ * 16 + (colg >> 6)) * 64 + (colg & 63))) << 11;
            *(bf16x8*)((bf16*)Yv + base + skv0 + rowc * 8) = v;
        }
    } else {
#pragma unroll
        for (int j = 0; j < 4; ++j) {
            const int col = n0 + nh + j * 16 + l16;
            const float bv = bias[col];
#pragma unroll
            for (int i = 0; i < 4; ++i)
#pragma unroll
                for (int r = 0; r < 4; ++r) {
                    int row = m0 + mh + i * 16 + quad * 4 + r;
                    float v = acc[i][j][r] + bv;
                    if constexpr (OM == 1)
                        ((float*)Yv)[(long)row * Nd + col] = v;
                    else
                        ((bf16*)Yv)[(long)row * Nd + col] = (bf16)v;
                }
        }
    }
}

// ---------------------------------------------------------------------------
// StableMax cross-attention, transposed-score formulation.
// One block per (b, h, 128-q tile); 4 waves, each owns 32 q (2 x 16 cols).
// S^T = K.Q^T via 16x16x32 bf16 MFMA  -> C-layout (row=kv, col=q)
//   == B-operand layout of 16x16x16 f16 MFMA (k=kv, n=q):
// stablemax in-register, pack f16, feed PV directly: ctx^T = V^T . P^T.
// No P LDS round-trip; den is a per-lane scalar, 2-shfl reduce at the end.
// ---------------------------------------------------------------------------
__global__ __launch_bounds__(256) void attn_kernel(
    const bf16* __restrict__ Q, const bf16* __restrict__ K,
    const f16* __restrict__ Vt, bf16* __restrict__ C) {
    constexpr int E = 1024, S = 2048;
    __shared__ __align__(16) bf16 Ks[128 * 72];   // [kv][d]  (pad 8)
    __shared__ __align__(16) f16 VTs[64 * 136];   // [d][kv]  (pad 8)

    const int tid = threadIdx.x;
    const int wid = tid >> 6, lane = tid & 63;
    const int l16 = lane & 15, quad = lane >> 4;
    const int qt = blockIdx.x, h = blockIdx.y, b = blockIdx.z;

    const long q0 = (long)b * S + qt * 128;
    const bf16* Qg = Q + q0 * E + h * 64;
    const bf16* Kg = K + (long)b * S * E + h * 64;
    const f16* Vg = Vt + ((long)(b * 16 + h) << 17);  // [d][2048]

    // Q B-fragments: B[k=d=quad*8+j][n=q=l16], 2 q-tiles (mt) x 2 k-chunks
    bf16x8 qf[2][2];
#pragma unroll
    for (int mt = 0; mt < 2; ++mt)
#pragma unroll
        for (int kc = 0; kc < 2; ++kc)
            qf[mt][kc] = *(const bf16x8*)(Qg + (long)(wid * 32 + mt * 16 + l16) * E + kc * 32 + quad * 8);

    f32x4 ctx[2][4];   // ctx^T [mt][dt]: lane holds d=dt*16+quad*4+r, q=l16
    float den[2] = {0.f, 0.f};
#pragma unroll
    for (int mt = 0; mt < 2; ++mt)
#pragma unroll
        for (int dt = 0; dt < 4; ++dt) ctx[mt][dt] = (f32x4){0.f, 0.f, 0.f, 0.f};

    const int srow = tid >> 2, sq = tid & 3;  // 4 threads per staged row

    for (int kv0 = 0; kv0 < S; kv0 += 128) {
        // stage K [128 kv][64 d]: 4 threads x 16 bf16 per row
#pragma unroll
        for (int rr = 0; rr < 2; ++rr) {
            const int r = rr * 64 + srow;
            const bf16* kp = Kg + (long)(kv0 + r) * E + sq * 16;
            *(bf16x8*)&Ks[r * 72 + sq * 16] = *(const bf16x8*)kp;
            *(bf16x8*)&Ks[r * 72 + sq * 16 + 8] = *(const bf16x8*)(kp + 8);
        }
        // stage V^T [64 d][128 kv]: 4 threads x 32 halves per row (4 x 16B)
        {
            const f16* vp = Vg + (long)srow * S + kv0 + sq * 32;
            *(f16x8*)&VTs[srow * 136 + sq * 32 + 0]  = *(const f16x8*)(vp + 0);
            *(f16x8*)&VTs[srow * 136 + sq * 32 + 8]  = *(const f16x8*)(vp + 8);
            *(f16x8*)&VTs[srow * 136 + sq * 32 + 16] = *(const f16x8*)(vp + 16);
            *(f16x8*)&VTs[srow * 136 + sq * 32 + 24] = *(const f16x8*)(vp + 24);
        }
        __syncthreads();

#pragma unroll
        for (int kvm = 0; kvm < 8; ++kvm) {
            // K A-fragments: A[m=kv=l16][k=d=quad*8+j]
            bf16x8 kf0 = *(const bf16x8*)&Ks[(kvm * 16 + l16) * 72 + quad * 8];
            bf16x8 kf1 = *(const bf16x8*)&Ks[(kvm * 16 + l16) * 72 + 32 + quad * 8];

            f16x4 pp[2];
#pragma unroll
            for (int mt = 0; mt < 2; ++mt) {
                f32x4 sacc = mfma_qk(kf0, qf[mt][0], (f32x4){0.f, 0.f, 0.f, 0.f});
                sacc = mfma_qk(kf1, qf[mt][1], sacc);
                // stablemax: u = 1 + |x|/8 ; s = x>=0 ? u : 1/u
#pragma unroll
                for (int r = 0; r < 4; ++r) {
                    float x = sacc[r];
                    float u = __builtin_fmaf(__builtin_fabsf(x), 0.125f, 1.0f);
                    float sv = (x >= 0.f) ? u : __builtin_amdgcn_rcpf(u);
                    den[mt] += sv;
                    pp[mt][r] = (f16)sv;
                }
            }
            // PV: ctx^T += V^T-frag x P^T-frag  (16x16x16 f16)
#pragma unroll
            for (int dt = 0; dt < 4; ++dt) {
                f16x4 vf = *(const f16x4*)&VTs[(dt * 16 + l16) * 136 + kvm * 16 + quad * 4];
#pragma unroll
                for (int mt = 0; mt < 2; ++mt)
                    ctx[mt][dt] = mfma_pv(vf, pp[mt], ctx[mt][dt]);
            }
        }
        __syncthreads();
    }

    // den: reduce across the 4 quads holding the same q column
    float scl[2];
#pragma unroll
    for (int mt = 0; mt < 2; ++mt) {
        float d = den[mt];
        d += __shfl_xor(d, 16);
        d += __shfl_xor(d, 32);
        scl[mt] = __builtin_amdgcn_rcpf(d);
    }

    // epilogue: ctx^T -> LDS transpose (reuse Ks, stride 68) -> coalesced store
    bf16* Os = Ks;
#pragma unroll
    for (int mt = 0; mt < 2; ++mt)
#pragma unroll
        for (int dt = 0; dt < 4; ++dt) {
            bf16x4 o;
#pragma unroll
            for (int r = 0; r < 4; ++r) o[r] = (bf16)(ctx[mt][dt][r] * scl[mt]);
            *(bf16x4*)&Os[(wid * 32 + mt * 16 + l16) * 68 + dt * 16 + quad * 4] = o;
        }
    __syncthreads();
    {
        const int r = tid >> 1, c = (tid & 1) * 32;
        bf16* cp = C + (q0 + r) * E + h * 64 + c;
#pragma unroll
        for (int j = 0; j < 4; ++j)
            *(bf16x8*)(cp + j * 8) = *(const bf16x8*)&Os[r * 68 + c + j * 8];
    }
}

// ---------------------------------------------------------------------------
extern "C" void kernel_launch(void* const* d_in, const int* in_sizes, int n_in,
                              void* d_out, int out_size, void* d_ws, size_t ws_size,
                              hipStream_t stream) {
    const float* query = (const float*)d_in[0];
    const float* keyv  = (const float*)d_in[1];
    const float* Wq = (const float*)d_in[2];
    const float* bq = (const float*)d_in[3];
    const float* Wk = (const float*)d_in[4];
    const float* bk = (const float*)d_in[5];
    const float* Wv = (const float*)d_in[6];
    const float* bv = (const float*)d_in[7];
    const float* Wo = (const float*)d_in[8];
    const float* bo = (const float*)d_in[9];

    char* ws = (char*)d_ws;
    bf16* Wb  = (bf16*)ws;                  // 8 MB: Wq,Wk,Wv,Wo bf16
    bf16* KVa = (bf16*)(ws + (8l << 20));   // 16 MB key_value bf16 (reused as Cw)
    bf16* Qw  = (bf16*)(ws + (24l << 20));  // 16 MB
    bf16* Kw  = (bf16*)(ws + (40l << 20));  // 16 MB
    f16*  Vt  = (f16*)(ws + (56l << 20));   // 16 MB V^T fp16 [b,h,d,skv]
    bf16* Cw  = KVa;                        // alias: KVa dead after V-GEMM

    cast_inputs<<<12288, 256, 0, stream>>>(Wq, Wk, Wv, Wo, keyv, Wb, KVa);

    dim3 gg(8, 64);  // N/128, M/128
    gemm_bt<float, 0><<<gg, 256, 0, stream>>>(query, Wb, bq, Qw);
    gemm_bt<bf16, 0><<<gg, 256, 0, stream>>>(KVa, Wb + (1l << 20), bk, Kw);
    gemm_bt<bf16, 2><<<gg, 256, 0, stream>>>(KVa, Wb + (2l << 20), bv, Vt);

    attn_kernel<<<dim3(16, 16, 4), 256, 0, stream>>>(Qw, Kw, Vt, Cw);

    gemm_bt<bf16, 1><<<gg, 256, 0, stream>>>(Cw, Wb + (3l << 20), bo, (float*)d_out);
}

// Round 7
// 349.262 us; speedup vs baseline: 1.1230x; 1.1230x over previous
//
#include <hip/hip_runtime.h>

typedef __bf16 bf16;
typedef __bf16 bf16x8 __attribute__((ext_vector_type(8)));
typedef __bf16 bf16x4 __attribute__((ext_vector_type(4)));
typedef _Float16 f16;
typedef _Float16 f16x2 __attribute__((ext_vector_type(2)));
typedef _Float16 f16x4 __attribute__((ext_vector_type(4)));
typedef float f32x4 __attribute__((ext_vector_type(4)));

__device__ __forceinline__ f32x4 mfma_qk(bf16x8 a, bf16x8 b, f32x4 c) {
    return __builtin_amdgcn_mfma_f32_16x16x32_bf16(a, b, c, 0, 0, 0);
}
__device__ __forceinline__ f32x4 mfma_pv(f16x4 a, f16x4 b, f32x4 c) {
    return __builtin_amdgcn_mfma_f32_16x16x16f16(a, b, c, 0, 0, 0);
}

// async global -> LDS, 16 bytes per lane (dest = wave-uniform base + lane*16)
#define GLOAD_LDS16(gp, lp)                                                    \
    __builtin_amdgcn_global_load_lds(                                          \
        (const __attribute__((address_space(1))) unsigned int*)(gp),           \
        (__attribute__((address_space(3))) unsigned int*)(lp), 16, 0, 0)

// ---------------------------------------------------------------------------
// Cast fp32 -> bf16: 4 weights (1024^2 each), key_value (8M), query (8M).
// ---------------------------------------------------------------------------
__global__ __launch_bounds__(256) void cast_inputs(
    const float* __restrict__ w0, const float* __restrict__ w1,
    const float* __restrict__ w2, const float* __restrict__ w3,
    const float* __restrict__ kv, const float* __restrict__ q,
    bf16* __restrict__ Wb, bf16* __restrict__ KVa, bf16* __restrict__ Qb) {
    long i4 = (long)blockIdx.x * 256 + threadIdx.x;  // float4 index
    const float* src;
    bf16* dst;
    long loc;
    if (i4 < 1048576) {            // 4 weights x 262144 float4
        int which = (int)(i4 >> 18);
        loc = (i4 & 262143) << 2;
        src = which == 0 ? w0 : which == 1 ? w1 : which == 2 ? w2 : w3;
        dst = Wb + ((long)which << 20);
    } else if (i4 < 3145728) {     // key_value
        loc = (i4 - 1048576) << 2;
        src = kv; dst = KVa;
    } else {                       // query
        loc = (i4 - 3145728) << 2;
        src = q; dst = Qb;
    }
    float4 f = *(const float4*)(src + loc);
    bf16x4 o;
    o[0] = (bf16)f.x; o[1] = (bf16)f.y; o[2] = (bf16)f.z; o[3] = (bf16)f.w;
    *(bf16x4*)(dst + loc) = o;
}

// ---------------------------------------------------------------------------
// Core GEMM: C[M,N] = A[M,K] @ W[N,K]^T + bias. M=8192, N=K=1024.
// 128x128 tile, BK=64, 4 waves each 64x64. Async global->LDS staging into
// XOR-swizzled pad-free layout: slot(row, c8) = row*8 + (c8 ^ (row&7));
// fragment b128 reads then spread over 8 bank-groups (conflict-free).
// om: 0 = bf16 row-major, 1 = f32 row-major, 2 = f16 V^T [b,h,d,skv].
// ---------------------------------------------------------------------------
__device__ __forceinline__ void gemm_core(
    const bf16* __restrict__ A, const bf16* __restrict__ Wt,
    const float* __restrict__ bias, void* __restrict__ Yv,
    const int om, bf16* smem, const int n0, const int m0) {
    constexpr int Kd = 1024, Nd = 1024;
    constexpr int TP = 132;  // om2 transpose row stride
    bf16* As = smem;          // 8192 halves (128 x 64, swizzled)
    bf16* Bs = smem + 8192;
    const int tid = threadIdx.x;
    const int wid = tid >> 6, lane = tid & 63;
    const int l16 = lane & 15, quad = lane >> 4;
    const int mh = (wid >> 1) * 64, nh = (wid & 1) * 64;

    f32x4 acc[4][4];
#pragma unroll
    for (int i = 0; i < 4; ++i)
#pragma unroll
        for (int j = 0; j < 4; ++j) acc[i][j] = (f32x4){0.f, 0.f, 0.f, 0.f};

    for (int k0 = 0; k0 < Kd; k0 += 64) {
#pragma unroll
        for (int j = 0; j < 4; ++j) {
            const int s = j * 256 + tid;
            const int r = s >> 3, c8 = (s & 7) ^ (r & 7);
            GLOAD_LDS16(A + (long)(m0 + r) * Kd + k0 + c8 * 8, &As[s * 8]);
            GLOAD_LDS16(Wt + (long)(n0 + r) * Kd + k0 + c8 * 8, &Bs[s * 8]);
        }
        __syncthreads();
#pragma unroll
        for (int kc = 0; kc < 2; ++kc) {
            bf16x8 af[4], bq[4];
#pragma unroll
            for (int i = 0; i < 4; ++i) {
                const int row = mh + i * 16 + l16;
                af[i] = *(const bf16x8*)&As[(row * 8 + ((kc * 4 + quad) ^ (row & 7))) * 8];
            }
#pragma unroll
            for (int i = 0; i < 4; ++i) {
                const int row = nh + i * 16 + l16;
                bq[i] = *(const bf16x8*)&Bs[(row * 8 + ((kc * 4 + quad) ^ (row & 7))) * 8];
            }
#pragma unroll
            for (int i = 0; i < 4; ++i)
#pragma unroll
                for (int j = 0; j < 4; ++j)
                    acc[i][j] = mfma_qk(af[i], bq[j], acc[i][j]);
        }
        __syncthreads();
    }

    if (om == 2) {
        // transpose tile through LDS as f16, then coalesced 16B stores
#pragma unroll
        for (int j = 0; j < 4; ++j) {
            const int col = nh + j * 16 + l16;
            const float bv = bias[n0 + col];
#pragma unroll
            for (int i = 0; i < 4; ++i)
#pragma unroll
                for (int p = 0; p < 2; ++p) {
                    f16x2 pk2;
                    pk2[0] = (f16)(acc[i][j][p * 2 + 0] + bv);
                    pk2[1] = (f16)(acc[i][j][p * 2 + 1] + bv);
                    *(f16x2*)&smem[col * TP + mh + i * 16 + quad * 4 + p * 2] = pk2;
                }
        }
        __syncthreads();
        // Vt[((b*16+h)*64+d)*2048 + skv]
        const int b_ = m0 >> 11, skv0 = m0 & 2047;
        const int rowc = tid & 15;
#pragma unroll
        for (int c = 0; c < 8; ++c) {
            const int col = (tid >> 4) + c * 16;
            const int colg = n0 + col;
            bf16x8 v = *(const bf16x8*)&smem[col * TP + rowc * 8];
            const long base = ((long)((b_ * 16 + (colg >> 6)) * 64 + (colg & 63))) << 11;
            *(bf16x8*)((bf16*)Yv + base + skv0 + rowc * 8) = v;
        }
    } else {
#pragma unroll
        for (int j = 0; j < 4; ++j) {
            const int col = n0 + nh + j * 16 + l16;
            const float bv = bias[col];
#pragma unroll
            for (int i = 0; i < 4; ++i)
#pragma unroll
                for (int r = 0; r < 4; ++r) {
                    int row = m0 + mh + i * 16 + quad * 4 + r;
                    float v = acc[i][j][r] + bv;
                    if (om == 1)
                        ((float*)Yv)[(long)row * Nd + col] = v;
                    else
                        ((bf16*)Yv)[(long)row * Nd + col] = (bf16)v;
                }
        }
    }
}

__global__ __launch_bounds__(256) void proj_q(
    const bf16* __restrict__ Qb, const bf16* __restrict__ Wq,
    const float* __restrict__ bq, bf16* __restrict__ Qw) {
    __shared__ __align__(16) bf16 smem[16896];
    gemm_core(Qb, Wq, bq, Qw, 0, smem, blockIdx.x * 128, blockIdx.y * 128);
}

__global__ __launch_bounds__(256) void proj_kv(
    const bf16* __restrict__ KVa,
    const bf16* __restrict__ Wk, const float* __restrict__ bk, bf16* __restrict__ Kw,
    const bf16* __restrict__ Wv, const float* __restrict__ bv, f16* __restrict__ Vt) {
    __shared__ __align__(16) bf16 smem[16896];
    if (blockIdx.z == 0)
        gemm_core(KVa, Wk, bk, Kw, 0, smem, blockIdx.x * 128, blockIdx.y * 128);
    else
        gemm_core(KVa, Wv, bv, Vt, 2, smem, blockIdx.x * 128, blockIdx.y * 128);
}

__global__ __launch_bounds__(256) void gemm_o(
    const bf16* __restrict__ Cw, const bf16* __restrict__ Wo,
    const float* __restrict__ bo, float* __restrict__ out) {
    __shared__ __align__(16) bf16 smem[16896];
    gemm_core(Cw, Wo, bo, out, 1, smem, blockIdx.x * 128, blockIdx.y * 128);
}

// ---------------------------------------------------------------------------
// StableMax cross-attention, transposed-score formulation (validated R6).
// Async GLOAD staging into XOR-swizzled pad-free LDS for K and V^T.
// ---------------------------------------------------------------------------
__global__ __launch_bounds__(256) void attn_kernel(
    const bf16* __restrict__ Q, const bf16* __restrict__ K,
    const f16* __restrict__ Vt, bf16* __restrict__ C) {
    constexpr int E = 1024, S = 2048;
    __shared__ __align__(16) char smem_raw[32768];
    bf16* Ks = (bf16*)smem_raw;             // [128 kv][64 d], swizzled chunks
    f16* VTs = (f16*)(smem_raw + 16384);    // [64 d][128 kv], swizzled chunks

    const int tid = threadIdx.x;
    const int wid = tid >> 6, lane = tid & 63;
    const int l16 = lane & 15, quad = lane >> 4;
    const int qt = blockIdx.x, h = blockIdx.y, b = blockIdx.z;

    const long q0 = (long)b * S + qt * 128;
    const bf16* Qg = Q + q0 * E + h * 64;
    const bf16* Kg = K + (long)b * S * E + h * 64;
    const f16* Vg = Vt + ((long)(b * 16 + h) << 17);  // [d][2048]

    // Q B-fragments: B[k=d=quad*8+j][n=q=l16]
    bf16x8 qf[2][2];
#pragma unroll
    for (int mt = 0; mt < 2; ++mt)
#pragma unroll
        for (int kc = 0; kc < 2; ++kc)
            qf[mt][kc] = *(const bf16x8*)(Qg + (long)(wid * 32 + mt * 16 + l16) * E + kc * 32 + quad * 8);

    f32x4 ctx[2][4];   // ctx^T: lane holds d=dt*16+quad*4+r, q=l16
    float den[2] = {0.f, 0.f};
#pragma unroll
    for (int mt = 0; mt < 2; ++mt)
#pragma unroll
        for (int dt = 0; dt < 4; ++dt) ctx[mt][dt] = (f32x4){0.f, 0.f, 0.f, 0.f};

    for (int kv0 = 0; kv0 < S; kv0 += 128) {
        // stage K [128 kv][64 d]: swizzle slot = r*8 + (c8 ^ (r&7))
#pragma unroll
        for (int j = 0; j < 4; ++j) {
            const int s = j * 256 + tid;
            const int r = s >> 3, c8 = (s & 7) ^ (r & 7);
            GLOAD_LDS16(Kg + (long)(kv0 + r) * E + c8 * 8, &Ks[s * 8]);
        }
        // stage V^T [64 d][128 kv]: slot = r*16 + (c16 ^ (r&15))
#pragma unroll
        for (int j = 0; j < 4; ++j) {
            const int s = j * 256 + tid;
            const int r = s >> 4, c16 = (s & 15) ^ (r & 15);
            GLOAD_LDS16(Vg + (long)r * S + kv0 + c16 * 8, &VTs[s * 8]);
        }
        __syncthreads();

#pragma unroll
        for (int kvm = 0; kvm < 8; ++kvm) {
            // K A-fragments: A[m=kv=l16][k=d=quad*8+j], swizzled chunk fetch
            const int rk = kvm * 16 + l16, rb = rk & 7;
            bf16x8 kf0 = *(const bf16x8*)&Ks[(rk * 8 + (quad ^ rb)) * 8];
            bf16x8 kf1 = *(const bf16x8*)&Ks[(rk * 8 + ((quad + 4) ^ rb)) * 8];

            f16x4 pp[2];
#pragma unroll
            for (int mt = 0; mt < 2; ++mt) {
                f32x4 sacc = mfma_qk(kf0, qf[mt][0], (f32x4){0.f, 0.f, 0.f, 0.f});
                sacc = mfma_qk(kf1, qf[mt][1], sacc);
                // stablemax: u = 1 + |x|/8 ; s = x>=0 ? u : 1/u
#pragma unroll
                for (int r = 0; r < 4; ++r) {
                    float x = sacc[r];
                    float u = __builtin_fmaf(__builtin_fabsf(x), 0.125f, 1.0f);
                    float sv = (x >= 0.f) ? u : __builtin_amdgcn_rcpf(u);
                    den[mt] += sv;
                    pp[mt][r] = (f16)sv;
                }
            }
            // PV: ctx^T += V^T-frag x P^T-frag (16x16x16 f16)
            const int c16 = 2 * kvm + (quad >> 1);
            const int ho = (quad & 1) * 4;
#pragma unroll
            for (int dt = 0; dt < 4; ++dt) {
                const int rv = dt * 16 + l16;
                f16x4 vf = *(const f16x4*)&VTs[(rv * 16 + (c16 ^ l16)) * 8 + ho];
#pragma unroll
                for (int mt = 0; mt < 2; ++mt)
                    ctx[mt][dt] = mfma_pv(vf, pp[mt], ctx[mt][dt]);
            }
        }
        __syncthreads();
    }

    // den: reduce across the 4 quads of each q column
    float scl[2];
#pragma unroll
    for (int mt = 0; mt < 2; ++mt) {
        float d = den[mt];
        d += __shfl_xor(d, 16);
        d += __shfl_xor(d, 32);
        scl[mt] = __builtin_amdgcn_rcpf(d);
    }

    // epilogue: ctx^T -> LDS transpose (overlay, stride 68) -> coalesced store
    bf16* Os = (bf16*)smem_raw;
#pragma unroll
    for (int mt = 0; mt < 2; ++mt)
#pragma unroll
        for (int dt = 0; dt < 4; ++dt) {
            bf16x4 o;
#pragma unroll
            for (int r = 0; r < 4; ++r) o[r] = (bf16)(ctx[mt][dt][r] * scl[mt]);
            *(bf16x4*)&Os[(wid * 32 + mt * 16 + l16) * 68 + dt * 16 + quad * 4] = o;
        }
    __syncthreads();
    {
        const int r = tid >> 1, c = (tid & 1) * 32;
        bf16* cp = C + (q0 + r) * E + h * 64 + c;
#pragma unroll
        for (int j = 0; j < 4; ++j)
            *(bf16x8*)(cp + j * 8) = *(const bf16x8*)&Os[r * 68 + c + j * 8];
    }
}

// ---------------------------------------------------------------------------
extern "C" void kernel_launch(void* const* d_in, const int* in_sizes, int n_in,
                              void* d_out, int out_size, void* d_ws, size_t ws_size,
                              hipStream_t stream) {
    const float* query = (const float*)d_in[0];
    const float* keyv  = (const float*)d_in[1];
    const float* Wq = (const float*)d_in[2];
    const float* bq = (const float*)d_in[3];
    const float* Wk = (const float*)d_in[4];
    const float* bk = (const float*)d_in[5];
    const float* Wv = (const float*)d_in[6];
    const float* bv = (const float*)d_in[7];
    const float* Wo = (const float*)d_in[8];
    const float* bo = (const float*)d_in[9];

    char* ws = (char*)d_ws;
    bf16* Wb  = (bf16*)ws;                  // 8 MB: Wq,Wk,Wv,Wo bf16
    bf16* KVa = (bf16*)(ws + (8l << 20));   // 16 MB kv bf16 (later Cw)
    bf16* Qb  = (bf16*)(ws + (24l << 20));  // 16 MB query bf16 (later Kw)
    bf16* Qw  = (bf16*)(ws + (40l << 20));  // 16 MB
    f16*  Vt  = (f16*)(ws + (56l << 20));   // 16 MB V^T f16 [b,h,d,skv]
    bf16* Kw  = Qb;                         // alias: Qb dead after proj_q
    bf16* Cw  = KVa;                        // alias: KVa dead after proj_kv

    cast_inputs<<<20480, 256, 0, stream>>>(Wq, Wk, Wv, Wo, keyv, query, Wb, KVa, Qb);

    dim3 gg(8, 64);
    proj_q<<<gg, 256, 0, stream>>>(Qb, Wb, bq, Qw);
    proj_kv<<<dim3(8, 64, 2), 256, 0, stream>>>(KVa, Wb + (1l << 20), bk, Kw,
                                                Wb + (2l << 20), bv, Vt);

    attn_kernel<<<dim3(16, 16, 4), 256, 0, stream>>>(Qw, Kw, Vt, Cw);

    gemm_o<<<gg, 256, 0, stream>>>(Cw, Wb + (3l << 20), bo, (float*)d_out);
}